// Round 11
// baseline (880.036 us; speedup 1.0000x reference)
//
#include <hip/hip_runtime.h>
#include <hip/hip_cooperative_groups.h>

namespace cg = cooperative_groups;

#define N1c 25000
#define N2c 5000
#define Dc 256
#define DOUTc 128
#define EPSc 1e-5f
#define NEGc 0.01f
#define CAPc 32            // bucket capacity; passing degree ~Poisson(3.2)

typedef __attribute__((ext_vector_type(8))) short short8;
typedef __attribute__((ext_vector_type(4))) float f32x4;

__device__ __forceinline__ ushort f2bf(float f) {
    unsigned u = __float_as_uint(f);
    u += 0x7fffu + ((u >> 16) & 1u);          // round-to-nearest-even
    return (ushort)(u >> 16);
}
__device__ __forceinline__ float bf2f(ushort u) {
    return __uint_as_float(((unsigned)u) << 16);
}
__device__ __forceinline__ unsigned pack2(float lo, float hi) {
    return ((unsigned)f2bf(lo)) | (((unsigned)f2bf(hi)) << 16);
}

// ============================ cooperative mega-kernel =======================
struct MegaParams {
    const float* x;
    const int *src0, *dst0, *val0, *src1, *dst1, *val1, *ts, *time_p, *itv_p;
    const float *W1l, *W1r, *b1, *g1, *bt1, *rm1, *rv1, *W2l, *W2r, *b2;
    int E0, E1;
    ushort *agg0, *h, *agg1, *Bt1, *Bt2;
    int *cnt0, *cnt1, *eidx0, *eidx1;
    float *mask_out, *out;
};

// gather one layer: one wave per dst row, grid-stride. SRC 0: fp32 X; 1: bf16 H.
template <int SRC>
__device__ __forceinline__ void gather_phase(
    const void* Xsrc, const int* cnt, const int* eidx,
    const int* src, const int* dst, const int* val, const int* ts,
    int t0, int iv, int E, ushort* agg, int n, int gw, int nw, int lane) {
    const float* Xf = (const float*)Xsrc;
    const ushort* Hb = (const ushort*)Xsrc;
    for (int row = gw; row < n; row += nw) {
        int c = cnt[row];
        int my = (lane < CAPc) ? eidx[row * CAPc + lane] : 0;
        my = (lane < c) ? my : 0;
        float4 a = make_float4(0.f, 0.f, 0.f, 0.f);
        float4 a2 = make_float4(0.f, 0.f, 0.f, 0.f);
        if (c <= CAPc) {
            int j = 0;
            for (; j + 1 < c; j += 2) {
                int s0 = __shfl(my, j, 64);
                int s1 = __shfl(my, j + 1, 64);
                if (SRC == 0) {
                    float4 v0 = *(const float4*)(Xf + (size_t)s0 * Dc + lane * 4);
                    float4 v1 = *(const float4*)(Xf + (size_t)s1 * Dc + lane * 4);
                    a.x += v0.x; a.y += v0.y; a.z += v0.z; a.w += v0.w;
                    a2.x += v1.x; a2.y += v1.y; a2.z += v1.z; a2.w += v1.w;
                } else {
                    ushort4 v0 = *(const ushort4*)(Hb + (size_t)s0 * Dc + lane * 4);
                    ushort4 v1 = *(const ushort4*)(Hb + (size_t)s1 * Dc + lane * 4);
                    a.x += bf2f(v0.x); a.y += bf2f(v0.y);
                    a.z += bf2f(v0.z); a.w += bf2f(v0.w);
                    a2.x += bf2f(v1.x); a2.y += bf2f(v1.y);
                    a2.z += bf2f(v1.z); a2.w += bf2f(v1.w);
                }
            }
            if (j < c) {
                int s0 = __shfl(my, j, 64);
                if (SRC == 0) {
                    float4 v0 = *(const float4*)(Xf + (size_t)s0 * Dc + lane * 4);
                    a.x += v0.x; a.y += v0.y; a.z += v0.z; a.w += v0.w;
                } else {
                    ushort4 v0 = *(const ushort4*)(Hb + (size_t)s0 * Dc + lane * 4);
                    a.x += bf2f(v0.x); a.y += bf2f(v0.y);
                    a.z += bf2f(v0.z); a.w += bf2f(v0.w);
                }
            }
        } else {
            // overflow fallback (statistically never taken; keeps any input correct)
            for (int e = 0; e < E; ++e) {
                if (dst[e] != row) continue;
                int t = ts[val[e]];
                if (t >= t0 && t < t0 + iv) {
                    if (SRC == 0) {
                        float4 v = *(const float4*)(Xf + (size_t)src[e] * Dc + lane * 4);
                        a.x += v.x; a.y += v.y; a.z += v.z; a.w += v.w;
                    } else {
                        ushort4 v = *(const ushort4*)(Hb + (size_t)src[e] * Dc + lane * 4);
                        a.x += bf2f(v.x); a.y += bf2f(v.y);
                        a.z += bf2f(v.z); a.w += bf2f(v.w);
                    }
                }
            }
        }
        a.x += a2.x; a.y += a2.y; a.z += a2.z; a.w += a2.w;
        float inv = 1.0f / fmaxf((float)c, 1.0f);
        ushort4 o;
        o.x = f2bf(a.x * inv); o.y = f2bf(a.y * inv);
        o.z = f2bf(a.z * inv); o.w = f2bf(a.w * inv);
        *(ushort4*)(agg + (size_t)row * Dc + lane * 4) = o;
    }
}

// one 32-row x full-N GEMM tile (validated R7 phase-2 structure).
// VARIANT 0: A=[agg0|bf16(x)], NJW=4 (N=256), out bf16 h + BN+leaky.
// VARIANT 1: A=[agg1|h],       NJW=2 (N=128), out fp32 + bias.
template <int VARIANT>
__device__ __forceinline__ void gemm_tile(
    ushort (*As)[536], int mt,
    const ushort* Alo, const void* A2, const ushort* Bt,
    const float* bias, const float* g, const float* bt,
    const float* rm, const float* rv, void* Cout, int M, int tid) {
    constexpr int NJW = (VARIANT == 0) ? 4 : 2;
    const int wave = tid >> 6, lane = tid & 63;
    const int quad = lane >> 4, l16 = lane & 15;
    const int m0 = mt * 32;
    // ---- stage A: wave stages rows wave*8 .. wave*8+7 (coalesced) ----
#pragma unroll
    for (int i = 0; i < 8; ++i) {
        int r = wave * 8 + i, m = m0 + r;
        if (m < M) {
            *(ushort4*)&As[r][lane * 4] =
                *(const ushort4*)(Alo + (size_t)m * Dc + lane * 4);
            if (VARIANT == 0) {
                float4 xf = *(const float4*)((const float*)A2 + (size_t)m * Dc + lane * 4);
                ushort4 ro;
                ro.x = f2bf(xf.x); ro.y = f2bf(xf.y);
                ro.z = f2bf(xf.z); ro.w = f2bf(xf.w);
                *(ushort4*)&As[r][256 + lane * 4] = ro;
            } else {
                *(ushort4*)&As[r][256 + lane * 4] =
                    *(const ushort4*)((const ushort*)A2 + (size_t)m * Dc + lane * 4);
            }
        } else {
            *(ushort4*)&As[r][lane * 4] = make_ushort4(0, 0, 0, 0);
            *(ushort4*)&As[r][256 + lane * 4] = make_ushort4(0, 0, 0, 0);
        }
    }
    __syncthreads();
    // ---- barrier-free k-loop: A from LDS, B direct from L2-resident Bt ----
    f32x4 acc[2][NJW] = {};
    const ushort* Bw = Bt + (size_t)((wave * NJW) * 16 + l16) * 512 + quad * 8;
    for (int k0 = 0; k0 < 512; k0 += 32) {
        short8 af[2];
        af[0] = *(const short8*)&As[l16][k0 + quad * 8];
        af[1] = *(const short8*)&As[16 + l16][k0 + quad * 8];
        uint4 bfr[NJW];
#pragma unroll
        for (int jj = 0; jj < NJW; ++jj)
            bfr[jj] = *(const uint4*)(Bw + (size_t)jj * 16 * 512 + k0);
#pragma unroll
        for (int jj = 0; jj < NJW; ++jj) {
            short8 bf = *reinterpret_cast<const short8*>(&bfr[jj]);
#pragma unroll
            for (int rt = 0; rt < 2; ++rt)
                acc[rt][jj] = __builtin_amdgcn_mfma_f32_16x16x32_bf16(af[rt], bf, acc[rt][jj], 0, 0, 0);
        }
    }
    __syncthreads();                      // As free for next tile / phase
    // ---- epilogue: C/D layout col=l16, row=quad*4+reg ----
#pragma unroll
    for (int jj = 0; jj < NJW; ++jj) {
        int gn = (wave * NJW + jj) * 16 + l16;
        float sc = 1.f, sh = bias[gn];
        if (VARIANT == 0) {
            float s = g[gn] * rsqrtf(rv[gn] + EPSc);
            sh = (bias[gn] - rm[gn]) * s + bt[gn];
            sc = s;
        }
#pragma unroll
        for (int rt = 0; rt < 2; ++rt) {
            int gmb = m0 + rt * 16 + quad * 4;
#pragma unroll
            for (int rr = 0; rr < 4; ++rr) {
                int gm = gmb + rr;
                if (gm >= M) continue;
                float v = acc[rt][jj][rr];
                if (VARIANT == 0) {
                    v = v * sc + sh;
                    v = v >= 0.f ? v : NEGc * v;
                    ((ushort*)Cout)[(size_t)gm * Dc + gn] = f2bf(v);
                } else {
                    ((float*)Cout)[(size_t)gm * DOUTc + gn] = v + sh;
                }
            }
        }
    }
}

__global__ __launch_bounds__(256, 4) void mega(MegaParams P) {
    cg::grid_group grid = cg::this_grid();
    __shared__ ushort As[32][536];        // 34304 B -> 4 blocks/CU guaranteed
    const int tid = threadIdx.x, bid = blockIdx.x, nb = gridDim.x;
    const int flat = bid * 256 + tid, NT = nb * 256;
    const int lane = tid & 63;
    const int gw = flat >> 6, nw = NT >> 6;
    const int t0 = *P.time_p, iv = *P.itv_p;

    // ---------- phase 0: zero cnt, W transposes (LDS-aliased), mask1 -------
    for (int i = flat; i < N1c + N2c; i += NT) {
        if (i < N1c) P.cnt0[i] = 0; else P.cnt1[i - N1c] = 0;
    }
    {
        float (*tl)[33] = (float (*)[33])As;
        const int tx = tid & 31, ty = tid >> 5;   // 32 x 8
        for (int t = bid; t < 192; t += nb) {
            const bool L1 = t < 128;
            const int tt = L1 ? t : t - 128;
            const int ntn = L1 ? 8 : 4;
            const int kt = tt / ntn, nt = tt % ntn;
            const int k0 = kt * 32, n0 = nt * 32;
            const float* Wl = L1 ? P.W1l : P.W2l;
            const float* Wr = L1 ? P.W1r : P.W2r;
            const int nst = L1 ? 256 : 128;
            ushort* Bt = L1 ? P.Bt1 : P.Bt2;
#pragma unroll
            for (int rr = 0; rr < 4; ++rr) {
                int r = ty * 4 + rr;
                int k = k0 + r;
                tl[r][tx] = (k < 256) ? Wl[(size_t)k * nst + n0 + tx]
                                      : Wr[(size_t)(k - 256) * nst + n0 + tx];
            }
            __syncthreads();
#pragma unroll
            for (int rr = 0; rr < 4; ++rr) {
                int r = ty * 4 + rr;
                Bt[(size_t)(n0 + r) * 512 + k0 + tx] = f2bf(tl[tx][r]);
            }
            __syncthreads();
        }
    }
    for (int e = flat; e < P.E1; e += NT) {
        int t = P.ts[P.val1[e]];
        P.mask_out[e] = (t >= t0 && t < t0 + iv) ? 1.0f : 0.0f;
    }
    grid.sync();

    // ---------- phase 1: single-pass bucketed CSR build ---------------------
    for (int e = flat; e < P.E0; e += NT) {
        int t = P.ts[P.val0[e]];
        if (t >= t0 && t < t0 + iv) {
            int d = P.dst0[e];
            int pos = atomicAdd(&P.cnt0[d], 1);
            if (pos < CAPc) P.eidx0[d * CAPc + pos] = P.src0[e];
        }
    }
    for (int e = flat; e < P.E1; e += NT) {
        int t = P.ts[P.val1[e]];
        if (t >= t0 && t < t0 + iv) {
            int d = P.dst1[e];
            int pos = atomicAdd(&P.cnt1[d], 1);
            if (pos < CAPc) P.eidx1[d * CAPc + pos] = P.src1[e];
        }
    }
    grid.sync();

    // ---------- phase 2: gather0 (fp32 x -> bf16 agg0) ----------------------
    gather_phase<0>(P.x, P.cnt0, P.eidx0, P.src0, P.dst0, P.val0, P.ts,
                    t0, iv, P.E0, P.agg0, N1c, gw, nw, lane);
    grid.sync();

    // ---------- phase 3: gemm1 (h = BN+leaky([agg0|x] @ Bt1^T + b1)) --------
    for (int mt = bid; mt * 32 < N1c; mt += nb)
        gemm_tile<0>(As, mt, P.agg0, P.x, P.Bt1, P.b1, P.g1, P.bt1, P.rm1, P.rv1,
                     P.h, N1c, tid);
    grid.sync();

    // ---------- phase 4: gather1 (bf16 h -> bf16 agg1) ----------------------
    gather_phase<1>(P.h, P.cnt1, P.eidx1, P.src1, P.dst1, P.val1, P.ts,
                    t0, iv, P.E1, P.agg1, N2c, gw, nw, lane);
    grid.sync();

    // ---------- phase 5: gemm2 (out = [agg1|h] @ Bt2^T + b2) ----------------
    for (int mt = bid; mt * 32 < N2c; mt += nb)
        gemm_tile<1>(As, mt, P.agg1, P.h, P.Bt2, P.b2, nullptr, nullptr, nullptr,
                     nullptr, P.out, N2c, tid);
}

// ===================== fallback path (R10, harness-proven) ==================
__global__ __launch_bounds__(256) void prep_fill(
    const int* __restrict__ src0, const int* __restrict__ dst0, const int* __restrict__ val0,
    const int* __restrict__ src1, const int* __restrict__ dst1, const int* __restrict__ val1,
    const int* __restrict__ ts, const int* __restrict__ time_p, const int* __restrict__ itv_p,
    const float* __restrict__ W1l, const float* __restrict__ W1r,
    const float* __restrict__ W2l, const float* __restrict__ W2r,
    int E0, int E1,
    ushort* __restrict__ Bt1, ushort* __restrict__ Bt2,
    int* __restrict__ cnt0, int* __restrict__ cnt1,
    int* __restrict__ eidx0, int* __restrict__ eidx1,
    float* __restrict__ mask_out) {
    const int flat = blockIdx.x * blockDim.x + threadIdx.x;
    const int NT = gridDim.x * blockDim.x;
    const int t0 = *time_p, iv = *itv_p;
    __shared__ float tl[32][33];
    const int tx = threadIdx.x & 31, ty = threadIdx.x >> 5;
    for (int t = blockIdx.x; t < 192; t += gridDim.x) {
        const bool L1 = t < 128;
        const int tt = L1 ? t : t - 128;
        const int ntn = L1 ? 8 : 4;
        const int kt = tt / ntn, nt = tt % ntn;
        const int k0 = kt * 32, n0 = nt * 32;
        const float* Wl = L1 ? W1l : W2l;
        const float* Wr = L1 ? W1r : W2r;
        const int nst = L1 ? 256 : 128;
        ushort* Bt = L1 ? Bt1 : Bt2;
#pragma unroll
        for (int rr = 0; rr < 4; ++rr) {
            int r = ty * 4 + rr;
            int k = k0 + r;
            tl[r][tx] = (k < 256) ? Wl[(size_t)k * nst + n0 + tx]
                                  : Wr[(size_t)(k - 256) * nst + n0 + tx];
        }
        __syncthreads();
#pragma unroll
        for (int rr = 0; rr < 4; ++rr) {
            int r = ty * 4 + rr;
            Bt[(size_t)(n0 + r) * 512 + k0 + tx] = f2bf(tl[tx][r]);
        }
        __syncthreads();
    }
    for (int e = flat; e < E0; e += NT) {
        int t = ts[val0[e]];
        if (t >= t0 && t < t0 + iv) {
            int d = dst0[e];
            int pos = atomicAdd(&cnt0[d], 1);
            if (pos < CAPc) eidx0[d * CAPc + pos] = src0[e];
        }
    }
    for (int e = flat; e < E1; e += NT) {
        int t = ts[val1[e]];
        bool m = (t >= t0 && t < t0 + iv);
        mask_out[e] = m ? 1.0f : 0.0f;
        if (m) {
            int d = dst1[e];
            int pos = atomicAdd(&cnt1[d], 1);
            if (pos < CAPc) eidx1[d * CAPc + pos] = src1[e];
        }
    }
}

template <int SRC>
__global__ void gather_k(const void* X, const int* __restrict__ cnt,
                         const int* __restrict__ eidx,
                         const int* __restrict__ src, const int* __restrict__ dst,
                         const int* __restrict__ val, const int* __restrict__ ts,
                         const int* __restrict__ time_p, const int* __restrict__ itv_p,
                         int E, ushort* __restrict__ agg, int n) {
    int wave = (blockIdx.x * blockDim.x + threadIdx.x) >> 6;
    int lane = threadIdx.x & 63;
    if (wave >= n) return;
    gather_phase<SRC>(X, cnt, eidx, src, dst, val, ts, *time_p, *itv_p, E,
                      agg, n, wave, 1 << 30, lane);
}

template <int VARIANT>
__global__ __launch_bounds__(256) void gemm_k(
    const ushort* __restrict__ Alo, const void* __restrict__ A2,
    const ushort* __restrict__ Bt, const float* __restrict__ bias,
    const float* __restrict__ g, const float* __restrict__ bt,
    const float* __restrict__ rm, const float* __restrict__ rv,
    void* __restrict__ Cout, int M) {
    __shared__ ushort As[32][536];
    gemm_tile<VARIANT>(As, blockIdx.x, Alo, A2, Bt, bias, g, bt, rm, rv, Cout, M,
                       threadIdx.x);
}

extern "C" void kernel_launch(void* const* d_in, const int* in_sizes, int n_in,
                              void* d_out, int out_size, void* d_ws, size_t ws_size,
                              hipStream_t stream) {
    const float* x    = (const float*)d_in[0];
    const int* src0   = (const int*)d_in[1];
    const int* dst0   = (const int*)d_in[2];
    const int* val0   = (const int*)d_in[3];
    const int* src1   = (const int*)d_in[4];
    const int* dst1   = (const int*)d_in[5];
    const int* val1   = (const int*)d_in[6];
    const int* ts     = (const int*)d_in[7];
    const int* time_p = (const int*)d_in[8];
    const int* itv_p  = (const int*)d_in[9];
    const float* W1l  = (const float*)d_in[10];
    const float* W1r  = (const float*)d_in[11];
    const float* b1   = (const float*)d_in[12];
    const float* g1   = (const float*)d_in[13];
    const float* bt1  = (const float*)d_in[14];
    const float* rm1  = (const float*)d_in[15];
    const float* rv1  = (const float*)d_in[16];
    const float* W2l  = (const float*)d_in[17];
    const float* W2r  = (const float*)d_in[18];
    const float* b2   = (const float*)d_in[19];
    int E0 = in_sizes[1];
    int E1 = in_sizes[4];
    float* out = (float*)d_out;

    // ---- workspace layout ----
    ushort* agg0 = (ushort*)d_ws;                  // [N1][256] bf16
    ushort* h    = agg0 + (size_t)N1c * Dc;        // [N1][256] bf16
    ushort* agg1 = h    + (size_t)N1c * Dc;        // [N2][256] bf16
    ushort* Bt1  = agg1 + (size_t)N2c * Dc;        // [256][512]
    ushort* Bt2  = Bt1  + 256 * 512;               // [128][512]
    int* ip      = (int*)(Bt2 + 128 * 512);
    int* cnt0    = ip;             ip += N1c;
    int* cnt1    = ip;             ip += N2c;
    int* eidx0   = ip;             ip += N1c * CAPc;
    int* eidx1   = ip;             ip += N2c * CAPc;
    float* mask_tail = out + (size_t)N2c * DOUTc;

    MegaParams P;
    P.x = x; P.src0 = src0; P.dst0 = dst0; P.val0 = val0;
    P.src1 = src1; P.dst1 = dst1; P.val1 = val1;
    P.ts = ts; P.time_p = time_p; P.itv_p = itv_p;
    P.W1l = W1l; P.W1r = W1r; P.b1 = b1; P.g1 = g1; P.bt1 = bt1;
    P.rm1 = rm1; P.rv1 = rv1; P.W2l = W2l; P.W2r = W2r; P.b2 = b2;
    P.E0 = E0; P.E1 = E1;
    P.agg0 = agg0; P.h = h; P.agg1 = agg1; P.Bt1 = Bt1; P.Bt2 = Bt2;
    P.cnt0 = cnt0; P.cnt1 = cnt1; P.eidx0 = eidx0; P.eidx1 = eidx1;
    P.mask_out = mask_tail; P.out = out;

    void* args[] = {&P};
    hipError_t err = hipLaunchCooperativeKernel(
        (const void*)mega, dim3(1024), dim3(256), args, 0, stream);

    if (err != hipSuccess) {
        // fallback: proven 5-kernel pipeline (R10)
        hipMemsetAsync(cnt0, 0, (size_t)(N1c + N2c) * sizeof(int), stream);
        prep_fill<<<2048, 256, 0, stream>>>(
            src0, dst0, val0, src1, dst1, val1, ts, time_p, itv_p,
            W1l, W1r, W2l, W2r, E0, E1, Bt1, Bt2,
            cnt0, cnt1, eidx0, eidx1, mask_tail);
        gather_k<0><<<(N1c + 3) / 4, 256, 0, stream>>>(
            x, cnt0, eidx0, src0, dst0, val0, ts, time_p, itv_p, E0, agg0, N1c);
        gemm_k<0><<<(N1c + 31) / 32, 256, 0, stream>>>(
            agg0, x, Bt1, b1, g1, bt1, rm1, rv1, h, N1c);
        gather_k<1><<<(N2c + 3) / 4, 256, 0, stream>>>(
            h, cnt1, eidx1, src1, dst1, val1, ts, time_p, itv_p, E1, agg1, N2c);
        gemm_k<1><<<(N2c + 31) / 32, 256, 0, stream>>>(
            agg1, h, Bt2, b2, nullptr, nullptr, nullptr, nullptr, out, N2c);
    }
}